// Round 4
// baseline (1188.783 us; speedup 1.0000x reference)
//
#include <hip/hip_runtime.h>

typedef __bf16 bf16_t;
typedef __bf16 bf16x8 __attribute__((ext_vector_type(8)));
typedef _Float16 f16x8 __attribute__((ext_vector_type(8)));
typedef unsigned short u16x8 __attribute__((ext_vector_type(8)));
typedef float f32x4 __attribute__((ext_vector_type(4)));

#define MT 64
#define NTHR 256
#define NBLK (1048576 / MT)

// LDS row stride = 256 cols * 2B = 512B. XOR-swizzle 16B slots by row.
__device__ __forceinline__ int swz(int row, int colbyte) {
  return row * 512 + (colbyte ^ ((row & 31) << 4));
}
__device__ __forceinline__ void st_act(unsigned short* buf, int row, int col, float v) {
  buf[swz(row, col * 2) >> 1] = __builtin_bit_cast(unsigned short, (bf16_t)v);
}
__device__ __forceinline__ bf16x8 ld_frag(const unsigned short* buf, int row, int kbyte) {
  const uint4 u =
      *reinterpret_cast<const uint4*>(reinterpret_cast<const char*>(buf) + swz(row, kbyte));
  return __builtin_bit_cast(bf16x8, u);
}

// ---------- prologue 1: transpose all 3 planes (32,H,W) fp32 -> (H*W,32) fp16 --
__global__ void KPlanes_tr3(const float* __restrict__ yx, const float* __restrict__ xt,
                            const float* __restrict__ yt, uint4* __restrict__ d0,
                            uint4* __restrict__ d1, uint4* __restrict__ d2) {
  const int HW0 = 518400, HW1 = 288000, HW2 = 162000;
  const int NB0 = 2025, NB1 = 1125;
  const int b = blockIdx.x;
  const float* src;
  uint4* dst;
  int HW, s;
  if (b < NB0) {
    src = yx; dst = d0; HW = HW0; s = b * 256 + threadIdx.x;
  } else if (b < NB0 + NB1) {
    src = xt; dst = d1; HW = HW1; s = (b - NB0) * 256 + threadIdx.x;
  } else {
    src = yt; dst = d2; HW = HW2; s = (b - NB0 - NB1) * 256 + threadIdx.x;
  }
  if (s >= HW) return;
#pragma unroll
  for (int g = 0; g < 4; ++g) {
    u16x8 v;
#pragma unroll
    for (int j = 0; j < 8; ++j) {
      const float w = src[(size_t)(g * 8 + j) * HW + s];
      v[j] = __builtin_bit_cast(unsigned short, (_Float16)w);
    }
    dst[(size_t)s * 4 + g] = __builtin_bit_cast(uint4, v);
  }
}

// ---------- prologue 2: pack ALL fp32 weights into bf16 MFMA B-fragments ------
__global__ void KPlanes_packall(const float* __restrict__ fw1, const float* __restrict__ fw2,
                                const float* __restrict__ w1, const float* __restrict__ w2,
                                const float* __restrict__ w3, const float* __restrict__ w4,
                                uint4* __restrict__ dst) {
  const int F = blockIdx.x * 4 + (threadIdx.x >> 6);
  const int lane = threadIdx.x & 63;
  if (F >= 340) return;
  const float* W;
  int N, K, KS, fbase;
  if (F < 4)        { W = fw1; N = 64;  K = 32;  KS = 1; fbase = 0; }
  else if (F < 12)  { W = fw2; N = 64;  K = 64;  KS = 2; fbase = 4; }
  else if (F < 76)  { W = w1;  N = 256; K = 119; KS = 4; fbase = 12; }
  else if (F < 204) { W = w2;  N = 256; K = 256; KS = 8; fbase = 76; }
  else if (F < 332) { W = w3;  N = 256; K = 256; KS = 8; fbase = 204; }
  else              { W = w4;  N = 3;   K = 256; KS = 8; fbase = 332; }
  const int f = F - fbase;
  const int g = f / KS, ks = f - g * KS;
  const int col = g * 16 + (lane & 15);
  u16x8 v;
#pragma unroll
  for (int j = 0; j < 8; ++j) {
    const int k = ks * 32 + (lane >> 4) * 8 + j;
    const float w = (k < K && col < N) ? W[(size_t)k * N + col] : 0.0f;
    v[j] = __builtin_bit_cast(unsigned short, (bf16_t)w);
  }
  dst[(size_t)F * 64 + lane] = __builtin_bit_cast(uint4, v);
}

// ---------- fp16 bilinear sample: load phase + combine phase ------------------
struct Smp {
  uint4 c00, c01, c10, c11;
  float w00, w01, w10, w11;
};
__device__ __forceinline__ Smp sample_ld(const uint4* __restrict__ plt, int Hd, int Wd, float u,
                                         float v, int q) {
  Smp s;
  float ix = fminf(fmaxf(u * (float)Wd - 0.5f, 0.f), (float)Wd - 1.f);
  float iy = fminf(fmaxf(v * (float)Hd - 0.5f, 0.f), (float)Hd - 1.f);
  float x0f = floorf(ix), y0f = floorf(iy);
  float wx = ix - x0f, wy = iy - y0f;
  int x0 = (int)x0f, y0 = (int)y0f;
  int x1 = min(x0 + 1, Wd - 1), y1 = min(y0 + 1, Hd - 1);
  s.w00 = (1.f - wx) * (1.f - wy);
  s.w01 = wx * (1.f - wy);
  s.w10 = (1.f - wx) * wy;
  s.w11 = wx * wy;
  const size_t r0 = (size_t)y0 * Wd, r1 = (size_t)y1 * Wd;
  s.c00 = plt[(r0 + x0) * 4 + q];
  s.c01 = plt[(r0 + x1) * 4 + q];
  s.c10 = plt[(r1 + x0) * 4 + q];
  s.c11 = plt[(r1 + x1) * 4 + q];
  return s;
}
__device__ __forceinline__ void smp_combine(const Smp& s, float* o) {
  const f16x8 a = __builtin_bit_cast(f16x8, s.c00);
  const f16x8 b = __builtin_bit_cast(f16x8, s.c01);
  const f16x8 c = __builtin_bit_cast(f16x8, s.c10);
  const f16x8 d = __builtin_bit_cast(f16x8, s.c11);
#pragma unroll
  for (int i = 0; i < 8; ++i)
    o[i] = (float)a[i] * s.w00 + (float)b[i] * s.w01 + (float)c[i] * s.w10 + (float)d[i] * s.w11;
}

// ---------- in-place MFMA layer ------------------------------------------------
// buf: 64 rows x 256 cols bf16 (swizzled). Computes full output into regs,
// barrier, stores in-place, barrier. Wave wid covers n-groups wid*NT..wid*NT+NT-1,
// all 4 m-tiles. Loop order: ks outer (A read once per (ks,m), bf transient).
template <int KS, int NT, bool RELU>
__device__ __forceinline__ void layer_ip(unsigned short* buf, const uint4* __restrict__ Wf,
                                         const float* __restrict__ bg, int wid, int lane) {
  const int l15 = lane & 15, lhi = lane >> 4;
  f32x4 acc[4][NT];
#pragma unroll
  for (int m = 0; m < 4; ++m)
#pragma unroll
    for (int t = 0; t < NT; ++t) acc[m][t] = f32x4{0.f, 0.f, 0.f, 0.f};
#pragma unroll
  for (int ks = 0; ks < KS; ++ks) {
    bf16x8 bf[NT];
#pragma unroll
    for (int t = 0; t < NT; ++t) {
      const int g = wid * NT + t;
      bf[t] = __builtin_bit_cast(bf16x8, Wf[(size_t)(g * KS + ks) * 64 + lane]);
    }
#pragma unroll
    for (int m = 0; m < 4; ++m) {
      const bf16x8 a = ld_frag(buf, m * 16 + l15, ks * 64 + lhi * 16);
#pragma unroll
      for (int t = 0; t < NT; ++t)
        acc[m][t] = __builtin_amdgcn_mfma_f32_16x16x32_bf16(a, bf[t], acc[m][t], 0, 0, 0);
    }
  }
  __syncthreads();  // all reads of buf complete across all waves
#pragma unroll
  for (int t = 0; t < NT; ++t) {
    const int col = (wid * NT + t) * 16 + l15;
    const float bias = bg[col];
#pragma unroll
    for (int m = 0; m < 4; ++m) {
      const int r0 = m * 16 + lhi * 4;
#pragma unroll
      for (int i = 0; i < 4; ++i) {
        float v = acc[m][t][i] + bias;
        if (RELU) v = fmaxf(v, 0.f);
        st_act(buf, r0 + i, col, v);
      }
    }
  }
  __syncthreads();  // stores visible before next layer reads
}

// ---------- main fused kernel: 64 points/block, 4 waves, 32 KB LDS ------------
__global__ __launch_bounds__(NTHR, 4) void KPlanes_fused4(
    const float* __restrict__ xyt, const uint4* __restrict__ yx_h, const uint4* __restrict__ xt_h,
    const uint4* __restrict__ yt_h, const uint4* __restrict__ wf1, const float* __restrict__ fb1,
    const uint4* __restrict__ wf2, const float* __restrict__ fb2, const uint4* __restrict__ wf3,
    const float* __restrict__ b1, const uint4* __restrict__ wf4, const float* __restrict__ b2,
    const uint4* __restrict__ wf5, const float* __restrict__ b3, const uint4* __restrict__ wf6,
    const float* __restrict__ b4, const int* __restrict__ fnum_p, float* __restrict__ out) {
  __shared__ unsigned short act[MT * 256];  // 32 KB, in-place across all layers
  const int tid = threadIdx.x;
  const int lane = tid & 63;
  const int wid = tid >> 6;
  const float fnum = (float)(*fnum_p);

  // ---- phase 0: gather (4 thr/point, 8 ch each) + pos-enc, into act
  {
    const int p = tid >> 2;
    const int q = tid & 3;
    const int pg = blockIdx.x * MT + p;
    const float x = xyt[pg * 3 + 0];
    const float y = xyt[pg * 3 + 1];
    const float t = xyt[pg * 3 + 2] / fnum;
    Smp sYX = sample_ld(yx_h, 540, 960, y, x, q);
    Smp sXT = sample_ld(xt_h, 960, 300, x, t, q);
    Smp sYT = sample_ld(yt_h, 540, 300, y, t, q);
    // pos-enc via one sincosf + double-angle recurrence (overlaps gather latency)
    if (q < 2) {
      const float base = q ? x : y;
      st_act(act, p, 64 + q, base);
      float sj, cj;
      sincosf(base, &sj, &cj);
#pragma unroll
      for (int j = 0; j < 10; ++j) {
        st_act(act, p, 66 + j * 4 + q, sj);
        st_act(act, p, 68 + j * 4 + q, cj);
        const float ns = 2.f * sj * cj;
        cj = fmaf(-2.f * sj, sj, 1.f);
        sj = ns;
      }
    } else if (q == 2) {
      st_act(act, p, 106, t);
      float sj, cj;
      sincosf(t, &sj, &cj);
#pragma unroll
      for (int j = 0; j < 6; ++j) {
        st_act(act, p, 107 + 2 * j, sj);
        st_act(act, p, 108 + 2 * j, cj);
        const float ns = 2.f * sj * cj;
        cj = fmaf(-2.f * sj, sj, 1.f);
        sj = ns;
      }
    } else {
#pragma unroll
      for (int cc = 119; cc < 128; ++cc) st_act(act, p, cc, 0.f);
    }
    float a8[8], b8[8], c8[8];
    smp_combine(sYX, a8);
    smp_combine(sXT, b8);
    smp_combine(sYT, c8);
#pragma unroll
    for (int i = 0; i < 8; ++i) st_act(act, p, q * 8 + i, a8[i] * b8[i] * c8[i]);
  }
  __syncthreads();
  // L1: feat(32)->h1(64): out cols 0..63 (pe cols 64..127 preserved)
  layer_ip<1, 1, true>(act, wf1, fb1, wid, lane);
  // L2: h1(64)->h2(64): cols 0..63
  layer_ip<2, 1, true>(act, wf2, fb2, wid, lane);
  // L3: [h2|pe](119 pad 128)->z1(256): overwrites whole buffer (pe dead)
  layer_ip<4, 4, true>(act, wf3, b1, wid, lane);
  // L4: z1->z2(256)
  layer_ip<8, 4, true>(act, wf4, b2, wid, lane);
  // L5: z2->z3(256)
  layer_ip<8, 4, true>(act, wf5, b3, wid, lane);
  // L6: z3(256)->3 (N pad 16), sigmoid, store. wave wid owns m-tile wid.
  {
    const int l15 = lane & 15, lhi = lane >> 4;
    f32x4 acc = {0.f, 0.f, 0.f, 0.f};
#pragma unroll
    for (int ks = 0; ks < 8; ++ks) {
      const bf16x8 bf6 = __builtin_bit_cast(bf16x8, wf6[ks * 64 + lane]);
      acc = __builtin_amdgcn_mfma_f32_16x16x32_bf16(
          ld_frag(act, wid * 16 + l15, ks * 64 + lhi * 16), bf6, acc, 0, 0, 0);
    }
    if (l15 < 3) {
      const float bb = b4[l15];
#pragma unroll
      for (int i = 0; i < 4; ++i) {
        const float v = acc[i] + bb;
        out[((size_t)blockIdx.x * MT + wid * 16 + lhi * 4 + i) * 3 + l15] =
            1.f / (1.f + expf(-v));
      }
    }
  }
}

// ================= fallback (fp32 weights, direct plane sampling) =============
__device__ __forceinline__ void sample8_f(const float* __restrict__ pl, int Hd, int Wd, float u,
                                          float v, int cgrp, float* o) {
  float ix = fminf(fmaxf(u * (float)Wd - 0.5f, 0.f), (float)Wd - 1.f);
  float iy = fminf(fmaxf(v * (float)Hd - 0.5f, 0.f), (float)Hd - 1.f);
  float x0f = floorf(ix), y0f = floorf(iy);
  float wx = ix - x0f, wy = iy - y0f;
  int x0 = (int)x0f, y0 = (int)y0f;
  int x1 = min(x0 + 1, Wd - 1), y1 = min(y0 + 1, Hd - 1);
  float w00 = (1.f - wx) * (1.f - wy), w01 = wx * (1.f - wy);
  float w10 = (1.f - wx) * wy, w11 = wx * wy;
  const size_t HW = (size_t)Hd * Wd;
#pragma unroll
  for (int i = 0; i < 8; ++i) {
    const float* bc = pl + (size_t)(cgrp + i) * HW;
    float a = bc[(size_t)y0 * Wd + x0], b = bc[(size_t)y0 * Wd + x1];
    float c = bc[(size_t)y1 * Wd + x0], d = bc[(size_t)y1 * Wd + x1];
    o[i] = a * w00 + b * w01 + c * w10 + d * w11;
  }
}

template <int KSTEPS, int NCPW, bool RELU>
__device__ __forceinline__ void mfma_layer_fb(const unsigned short* inb, unsigned short* outb,
                                              const float* __restrict__ Wg,
                                              const float* __restrict__ bg, int N, int Kmax,
                                              int wid, int lane) {
  const int l15 = lane & 15;
  const int lhi = lane >> 4;
#pragma unroll
  for (int t = 0; t < NCPW; ++t) {
    const int nc = wid * NCPW + t;
    const int col = nc * 16 + l15;
    const float bias = bg[col];
    bf16x8 bfrag[KSTEPS];
#pragma unroll
    for (int ks = 0; ks < KSTEPS; ++ks) {
#pragma unroll
      for (int j = 0; j < 8; ++j) {
        const int k = ks * 32 + lhi * 8 + j;
        float wv = (k < Kmax) ? Wg[(size_t)k * N + col] : 0.0f;
        bfrag[ks][j] = (bf16_t)wv;
      }
    }
#pragma unroll
    for (int m = 0; m < 4; ++m) {
      f32x4 acc = {0.f, 0.f, 0.f, 0.f};
#pragma unroll
      for (int ks = 0; ks < KSTEPS; ++ks) {
        bf16x8 a = ld_frag(inb, m * 16 + l15, ks * 64 + lhi * 16);
        acc = __builtin_amdgcn_mfma_f32_16x16x32_bf16(a, bfrag[ks], acc, 0, 0, 0);
      }
      const int r0 = m * 16 + lhi * 4;
#pragma unroll
      for (int i = 0; i < 4; ++i) {
        float v = acc[i] + bias;
        if (RELU) v = fmaxf(v, 0.f);
        st_act(outb, r0 + i, col, v);
      }
    }
  }
}

__global__ __launch_bounds__(256) void KPlanes_fused_fb(
    const float* __restrict__ xyt, const float* __restrict__ yx, const float* __restrict__ xt,
    const float* __restrict__ yt, const float* __restrict__ fw1, const float* __restrict__ fb1,
    const float* __restrict__ fw2, const float* __restrict__ fb2, const float* __restrict__ w1,
    const float* __restrict__ b1, const float* __restrict__ w2, const float* __restrict__ b2,
    const float* __restrict__ w3, const float* __restrict__ b3, const float* __restrict__ w4,
    const float* __restrict__ b4, const int* __restrict__ fnum_p, float* __restrict__ out) {
  __shared__ unsigned short actA[64 * 256];
  __shared__ unsigned short actB[64 * 256];
  const int tid = threadIdx.x;
  const int lane = tid & 63;
  const int wid = tid >> 6;
  const float fnum = (float)(*fnum_p);
  {
    const int p = tid >> 2;
    const int cgrp = (tid & 3) * 8;
    const int pg = blockIdx.x * 64 + p;
    float x = xyt[pg * 3 + 0];
    float y = xyt[pg * 3 + 1];
    float t = xyt[pg * 3 + 2] / fnum;
    float syx[8], sxt[8], syt[8];
    sample8_f(yx, 540, 960, y, x, cgrp, syx);
    sample8_f(xt, 960, 300, x, t, cgrp, sxt);
    sample8_f(yt, 540, 300, y, t, cgrp, syt);
#pragma unroll
    for (int i = 0; i < 8; ++i) st_act(actA, p, cgrp + i, syx[i] * sxt[i] * syt[i]);
  }
  __syncthreads();
  mfma_layer_fb<1, 1, true>(actA, actB, fw1, fb1, 64, 32, wid, lane);
  __syncthreads();
  mfma_layer_fb<2, 1, true>(actB, actA, fw2, fb2, 64, 64, wid, lane);
  if (tid < 64) {
    const int pg = blockIdx.x * 64 + tid;
    float px = xyt[pg * 3 + 0];
    float py = xyt[pg * 3 + 1];
    float pt = xyt[pg * 3 + 2] / fnum;
    st_act(actA, tid, 64, py);
    st_act(actA, tid, 65, px);
    float sc = 1.f;
#pragma unroll
    for (int j = 0; j < 10; ++j) {
      st_act(actA, tid, 66 + j * 4 + 0, sinf(sc * py));
      st_act(actA, tid, 66 + j * 4 + 1, sinf(sc * px));
      st_act(actA, tid, 66 + j * 4 + 2, cosf(sc * py));
      st_act(actA, tid, 66 + j * 4 + 3, cosf(sc * px));
      sc *= 2.f;
    }
    st_act(actA, tid, 106, pt);
    sc = 1.f;
#pragma unroll
    for (int j = 0; j < 6; ++j) {
      st_act(actA, tid, 107 + j * 2, sinf(sc * pt));
      st_act(actA, tid, 108 + j * 2, cosf(sc * pt));
      sc *= 2.f;
    }
#pragma unroll
    for (int c = 119; c < 128; ++c) st_act(actA, tid, c, 0.f);
  }
  __syncthreads();
  mfma_layer_fb<4, 4, true>(actA, actB, w1, b1, 256, 119, wid, lane);
  __syncthreads();
  mfma_layer_fb<8, 4, true>(actB, actA, w2, b2, 256, 256, wid, lane);
  __syncthreads();
  mfma_layer_fb<8, 4, true>(actA, actB, w3, b3, 256, 256, wid, lane);
  __syncthreads();
  {
    const int p = tid >> 2, c = tid & 3;
    if (c < 3) {
      float acc = 0.f;
#pragma unroll
      for (int k0 = 0; k0 < 256; k0 += 8) {
        int b = swz(p, k0 * 2);
        uint4 u = *reinterpret_cast<const uint4*>(reinterpret_cast<const char*>(actB) + b);
        bf16x8 z = __builtin_bit_cast(bf16x8, u);
#pragma unroll
        for (int j = 0; j < 8; ++j) acc += (float)z[j] * w4[(k0 + j) * 3 + c];
      }
      acc += b4[c];
      out[(size_t)(blockIdx.x * 64 + p) * 3 + c] = 1.f / (1.f + expf(-acc));
    }
  }
}

extern "C" void kernel_launch(void* const* d_in, const int* in_sizes, int n_in, void* d_out,
                              int out_size, void* d_ws, size_t ws_size, hipStream_t stream) {
  const float* xyt = (const float*)d_in[0];
  const float* yx = (const float*)d_in[1];
  const float* xt = (const float*)d_in[2];
  const float* yt = (const float*)d_in[3];
  const float* fw1 = (const float*)d_in[4];
  const float* fb1 = (const float*)d_in[5];
  const float* fw2 = (const float*)d_in[6];
  const float* fb2 = (const float*)d_in[7];
  const float* w1 = (const float*)d_in[8];
  const float* b1 = (const float*)d_in[9];
  const float* w2 = (const float*)d_in[10];
  const float* b2 = (const float*)d_in[11];
  const float* w3 = (const float*)d_in[12];
  const float* b3 = (const float*)d_in[13];
  const float* w4 = (const float*)d_in[14];
  const float* b4 = (const float*)d_in[15];
  const int* fnum = (const int*)d_in[16];
  float* out = (float*)d_out;

  const int hw_yx = 540 * 960, hw_xt = 960 * 300, hw_yt = 540 * 300;
  const size_t plane_bytes = ((size_t)hw_yx + hw_xt + hw_yt) * 64;  // fp16, 64B/site
  const size_t wfrag_bytes = (size_t)340 * 64 * sizeof(uint4);
  const size_t need = plane_bytes + wfrag_bytes;

  uint4* yx_h = (uint4*)d_ws;
  uint4* xt_h = yx_h + (size_t)hw_yx * 4;
  uint4* yt_h = xt_h + (size_t)hw_xt * 4;
  uint4* wbase = (uint4*)((char*)d_ws + plane_bytes);
  uint4* wf1 = wbase + 0 * 64;
  uint4* wf2 = wbase + 4 * 64;
  uint4* wf3 = wbase + 12 * 64;
  uint4* wf4 = wbase + 76 * 64;
  uint4* wf5 = wbase + 204 * 64;
  uint4* wf6 = wbase + 332 * 64;

  if (ws_size >= need) {
    const int nb_tr = 2025 + 1125 + 633;
    KPlanes_tr3<<<nb_tr, 256, 0, stream>>>(yx, xt, yt, yx_h, xt_h, yt_h);
    KPlanes_packall<<<85, 256, 0, stream>>>(fw1, fw2, w1, w2, w3, w4, wbase);
    KPlanes_fused4<<<NBLK, NTHR, 0, stream>>>(xyt, yx_h, xt_h, yt_h, wf1, fb1, wf2, fb2, wf3, b1,
                                              wf4, b2, wf5, b3, wf6, b4, fnum, out);
  } else {
    KPlanes_fused_fb<<<1048576 / 64, 256, 0, stream>>>(xyt, yx, xt, yt, fw1, fb1, fw2, fb2, w1,
                                                       b1, w2, b2, w3, b3, w4, b4, fnum, out);
  }
}

// Round 5
// 956.869 us; speedup vs baseline: 1.2424x; 1.2424x over previous
//
#include <hip/hip_runtime.h>

typedef __bf16 bf16_t;
typedef __bf16 bf16x8 __attribute__((ext_vector_type(8)));
typedef _Float16 f16x4 __attribute__((ext_vector_type(4)));
typedef unsigned short u16x8 __attribute__((ext_vector_type(8)));
typedef float f32x4 __attribute__((ext_vector_type(4)));

#define MT 64
#define NTHR 512
#define NBLK (1048576 / MT)

// LDS row stride = 256 cols * 2B = 512B. XOR-swizzle 16B slots by row.
__device__ __forceinline__ int swz(int row, int colbyte) {
  return row * 512 + (colbyte ^ ((row & 31) << 4));
}
__device__ __forceinline__ void st_act(unsigned short* buf, int row, int col, float v) {
  buf[swz(row, col * 2) >> 1] = __builtin_bit_cast(unsigned short, (bf16_t)v);
}
__device__ __forceinline__ bf16x8 ld_frag(const unsigned short* buf, int row, int kbyte) {
  const uint4 u =
      *reinterpret_cast<const uint4*>(reinterpret_cast<const char*>(buf) + swz(row, kbyte));
  return __builtin_bit_cast(bf16x8, u);
}

// ---------- prologue 1: transpose all 3 planes (32,H,W) fp32 -> (H*W,32) fp16 --
__global__ void KPlanes_tr3(const float* __restrict__ yx, const float* __restrict__ xt,
                            const float* __restrict__ yt, uint4* __restrict__ d0,
                            uint4* __restrict__ d1, uint4* __restrict__ d2) {
  const int HW0 = 518400, HW1 = 288000, HW2 = 162000;
  const int NB0 = 2025, NB1 = 1125;
  const int b = blockIdx.x;
  const float* src;
  uint4* dst;
  int HW, s;
  if (b < NB0) {
    src = yx; dst = d0; HW = HW0; s = b * 256 + threadIdx.x;
  } else if (b < NB0 + NB1) {
    src = xt; dst = d1; HW = HW1; s = (b - NB0) * 256 + threadIdx.x;
  } else {
    src = yt; dst = d2; HW = HW2; s = (b - NB0 - NB1) * 256 + threadIdx.x;
  }
  if (s >= HW) return;
#pragma unroll
  for (int g = 0; g < 4; ++g) {
    u16x8 v;
#pragma unroll
    for (int j = 0; j < 8; ++j) {
      const float w = src[(size_t)(g * 8 + j) * HW + s];
      v[j] = __builtin_bit_cast(unsigned short, (_Float16)w);
    }
    dst[(size_t)s * 4 + g] = __builtin_bit_cast(uint4, v);
  }
}

// ---------- prologue 2: pack ALL fp32 weights into bf16 MFMA B-fragments ------
__global__ void KPlanes_packall(const float* __restrict__ fw1, const float* __restrict__ fw2,
                                const float* __restrict__ w1, const float* __restrict__ w2,
                                const float* __restrict__ w3, const float* __restrict__ w4,
                                uint4* __restrict__ dst) {
  const int F = blockIdx.x * 4 + (threadIdx.x >> 6);
  const int lane = threadIdx.x & 63;
  if (F >= 340) return;
  const float* W;
  int N, K, KS, fbase;
  if (F < 4)        { W = fw1; N = 64;  K = 32;  KS = 1; fbase = 0; }
  else if (F < 12)  { W = fw2; N = 64;  K = 64;  KS = 2; fbase = 4; }
  else if (F < 76)  { W = w1;  N = 256; K = 119; KS = 4; fbase = 12; }
  else if (F < 204) { W = w2;  N = 256; K = 256; KS = 8; fbase = 76; }
  else if (F < 332) { W = w3;  N = 256; K = 256; KS = 8; fbase = 204; }
  else              { W = w4;  N = 3;   K = 256; KS = 8; fbase = 332; }
  const int f = F - fbase;
  const int g = f / KS, ks = f - g * KS;
  const int col = g * 16 + (lane & 15);
  u16x8 v;
#pragma unroll
  for (int j = 0; j < 8; ++j) {
    const int k = ks * 32 + (lane >> 4) * 8 + j;
    const float w = (k < K && col < N) ? W[(size_t)k * N + col] : 0.0f;
    v[j] = __builtin_bit_cast(unsigned short, (bf16_t)w);
  }
  dst[(size_t)F * 64 + lane] = __builtin_bit_cast(uint4, v);
}

// ---------- fp16 bilinear sample, 4 channels per thread -----------------------
struct Smp4 {
  uint2 c00, c01, c10, c11;
  float w00, w01, w10, w11;
};
__device__ __forceinline__ Smp4 sample_ld4(const uint2* __restrict__ plt, int Hd, int Wd, float u,
                                           float v, int q) {
  Smp4 s;
  float ix = fminf(fmaxf(u * (float)Wd - 0.5f, 0.f), (float)Wd - 1.f);
  float iy = fminf(fmaxf(v * (float)Hd - 0.5f, 0.f), (float)Hd - 1.f);
  float x0f = floorf(ix), y0f = floorf(iy);
  float wx = ix - x0f, wy = iy - y0f;
  int x0 = (int)x0f, y0 = (int)y0f;
  int x1 = min(x0 + 1, Wd - 1), y1 = min(y0 + 1, Hd - 1);
  s.w00 = (1.f - wx) * (1.f - wy);
  s.w01 = wx * (1.f - wy);
  s.w10 = (1.f - wx) * wy;
  s.w11 = wx * wy;
  const size_t r0 = (size_t)y0 * Wd, r1 = (size_t)y1 * Wd;
  s.c00 = plt[(r0 + x0) * 8 + q];
  s.c01 = plt[(r0 + x1) * 8 + q];
  s.c10 = plt[(r1 + x0) * 8 + q];
  s.c11 = plt[(r1 + x1) * 8 + q];
  return s;
}
__device__ __forceinline__ void smp_combine4(const Smp4& s, float* o) {
  const f16x4 a = __builtin_bit_cast(f16x4, s.c00);
  const f16x4 b = __builtin_bit_cast(f16x4, s.c01);
  const f16x4 c = __builtin_bit_cast(f16x4, s.c10);
  const f16x4 d = __builtin_bit_cast(f16x4, s.c11);
#pragma unroll
  for (int i = 0; i < 4; ++i)
    o[i] = (float)a[i] * s.w00 + (float)b[i] * s.w01 + (float)c[i] * s.w10 + (float)d[i] * s.w11;
}

// ---------- in-place MFMA layer, low register pressure ------------------------
// Wave computes acc[MTPW][NT] (<=32 regs); bf reloaded per ks (held across m).
template <int KS, int NT, int MTPW, bool RELU>
__device__ __forceinline__ void layer_ip(unsigned short* buf, const uint4* __restrict__ Wf,
                                         const float* __restrict__ bg, int gbase, int moff,
                                         int lane) {
  const int l15 = lane & 15, lhi = lane >> 4;
  f32x4 acc[MTPW][NT];
#pragma unroll
  for (int m = 0; m < MTPW; ++m)
#pragma unroll
    for (int t = 0; t < NT; ++t) acc[m][t] = f32x4{0.f, 0.f, 0.f, 0.f};
#pragma unroll
  for (int ks = 0; ks < KS; ++ks) {
    bf16x8 bf[NT];
#pragma unroll
    for (int t = 0; t < NT; ++t)
      bf[t] = __builtin_bit_cast(bf16x8, Wf[(size_t)((gbase + t) * KS + ks) * 64 + lane]);
#pragma unroll
    for (int m = 0; m < MTPW; ++m) {
      const bf16x8 a = ld_frag(buf, (moff + m) * 16 + l15, ks * 64 + lhi * 16);
#pragma unroll
      for (int t = 0; t < NT; ++t)
        acc[m][t] = __builtin_amdgcn_mfma_f32_16x16x32_bf16(a, bf[t], acc[m][t], 0, 0, 0);
    }
  }
  __syncthreads();  // all reads of buf complete across all waves
#pragma unroll
  for (int t = 0; t < NT; ++t) {
    const int col = (gbase + t) * 16 + l15;
    const float bias = bg[col];
#pragma unroll
    for (int m = 0; m < MTPW; ++m) {
      const int r0 = (moff + m) * 16 + lhi * 4;
#pragma unroll
      for (int i = 0; i < 4; ++i) {
        float v = acc[m][t][i] + bias;
        if (RELU) v = fmaxf(v, 0.f);
        st_act(buf, r0 + i, col, v);
      }
    }
  }
  __syncthreads();  // stores visible before next layer reads
}

// ---------- main fused kernel: 64 points/block, 8 waves, 32 KB LDS, 3 blk/CU --
__global__ __launch_bounds__(NTHR, 6) void KPlanes_fused5(
    const float* __restrict__ xyt, const uint2* __restrict__ yx_h, const uint2* __restrict__ xt_h,
    const uint2* __restrict__ yt_h, const uint4* __restrict__ wf1, const float* __restrict__ fb1,
    const uint4* __restrict__ wf2, const float* __restrict__ fb2, const uint4* __restrict__ wf3,
    const float* __restrict__ b1, const uint4* __restrict__ wf4, const float* __restrict__ b2,
    const uint4* __restrict__ wf5, const float* __restrict__ b3, const uint4* __restrict__ wf6,
    const float* __restrict__ b4, const int* __restrict__ fnum_p, float* __restrict__ out) {
  __shared__ unsigned short act[MT * 256];  // 32 KB, in-place across all layers
  const int tid = threadIdx.x;
  const int lane = tid & 63;
  const int wid = tid >> 6;
  const float fnum = (float)(*fnum_p);

  // ---- phase 0: gather (8 thr/point, 4 ch each) + pos-enc, into act
  {
    const int p = tid >> 3;
    const int q = tid & 7;
    const int pg = blockIdx.x * MT + p;
    const float x = xyt[pg * 3 + 0];
    const float y = xyt[pg * 3 + 1];
    const float t = xyt[pg * 3 + 2] / fnum;
    Smp4 sYX = sample_ld4(yx_h, 540, 960, y, x, q);
    Smp4 sXT = sample_ld4(xt_h, 960, 300, x, t, q);
    Smp4 sYT = sample_ld4(yt_h, 540, 300, y, t, q);
    // pos-enc on q=4..7 (overlaps gather latency); one sincosf + double-angle
    if (q == 4) {
      st_act(act, p, 64, y);
      float sj, cj;
      sincosf(y, &sj, &cj);
#pragma unroll
      for (int j = 0; j < 10; ++j) {
        st_act(act, p, 66 + j * 4, sj);
        st_act(act, p, 68 + j * 4, cj);
        const float ns = 2.f * sj * cj;
        cj = fmaf(-2.f * sj, sj, 1.f);
        sj = ns;
      }
    } else if (q == 5) {
      st_act(act, p, 65, x);
      float sj, cj;
      sincosf(x, &sj, &cj);
#pragma unroll
      for (int j = 0; j < 10; ++j) {
        st_act(act, p, 67 + j * 4, sj);
        st_act(act, p, 69 + j * 4, cj);
        const float ns = 2.f * sj * cj;
        cj = fmaf(-2.f * sj, sj, 1.f);
        sj = ns;
      }
    } else if (q == 6) {
      st_act(act, p, 106, t);
      float sj, cj;
      sincosf(t, &sj, &cj);
#pragma unroll
      for (int j = 0; j < 6; ++j) {
        st_act(act, p, 107 + 2 * j, sj);
        st_act(act, p, 108 + 2 * j, cj);
        const float ns = 2.f * sj * cj;
        cj = fmaf(-2.f * sj, sj, 1.f);
        sj = ns;
      }
    } else if (q == 7) {
#pragma unroll
      for (int cc = 119; cc < 128; ++cc) st_act(act, p, cc, 0.f);
    }
    float a4[4], b4_[4], c4[4];
    smp_combine4(sYX, a4);
    smp_combine4(sXT, b4_);
    smp_combine4(sYT, c4);
#pragma unroll
    for (int i = 0; i < 4; ++i) st_act(act, p, q * 4 + i, a4[i] * b4_[i] * c4[i]);
  }
  __syncthreads();
  // L1: feat(32)->h1(64): 4 col-groups x 2 m-halves across 8 waves
  layer_ip<1, 1, 2, true>(act, wf1, fb1, wid & 3, (wid >> 2) * 2, lane);
  // L2: h1(64)->h2(64): cols 0..63 (pe cols 64..127 preserved)
  layer_ip<2, 1, 2, true>(act, wf2, fb2, wid & 3, (wid >> 2) * 2, lane);
  // L3: [h2|pe](119 pad 128)->z1(256): wave owns 2 col-groups, all 4 m-tiles
  layer_ip<4, 2, 4, true>(act, wf3, b1, wid * 2, 0, lane);
  // L4: z1->z2(256)
  layer_ip<8, 2, 4, true>(act, wf4, b2, wid * 2, 0, lane);
  // L5: z2->z3(256)
  layer_ip<8, 2, 4, true>(act, wf5, b3, wid * 2, 0, lane);
  // L6: z3(256)->3 (N pad 16), sigmoid, store. Waves 0..3 own m-tiles.
  if (wid < 4) {
    const int l15 = lane & 15, lhi = lane >> 4;
    f32x4 acc = {0.f, 0.f, 0.f, 0.f};
#pragma unroll
    for (int ks = 0; ks < 8; ++ks) {
      const bf16x8 bf6 = __builtin_bit_cast(bf16x8, wf6[ks * 64 + lane]);
      acc = __builtin_amdgcn_mfma_f32_16x16x32_bf16(
          ld_frag(act, wid * 16 + l15, ks * 64 + lhi * 16), bf6, acc, 0, 0, 0);
    }
    if (l15 < 3) {
      const float bb = b4[l15];
#pragma unroll
      for (int i = 0; i < 4; ++i) {
        const float v = acc[i] + bb;
        out[((size_t)blockIdx.x * MT + wid * 16 + lhi * 4 + i) * 3 + l15] =
            1.f / (1.f + expf(-v));
      }
    }
  }
}

// ================= fallback (fp32 weights, direct plane sampling) =============
__device__ __forceinline__ void sample8_f(const float* __restrict__ pl, int Hd, int Wd, float u,
                                          float v, int cgrp, float* o) {
  float ix = fminf(fmaxf(u * (float)Wd - 0.5f, 0.f), (float)Wd - 1.f);
  float iy = fminf(fmaxf(v * (float)Hd - 0.5f, 0.f), (float)Hd - 1.f);
  float x0f = floorf(ix), y0f = floorf(iy);
  float wx = ix - x0f, wy = iy - y0f;
  int x0 = (int)x0f, y0 = (int)y0f;
  int x1 = min(x0 + 1, Wd - 1), y1 = min(y0 + 1, Hd - 1);
  float w00 = (1.f - wx) * (1.f - wy), w01 = wx * (1.f - wy);
  float w10 = (1.f - wx) * wy, w11 = wx * wy;
  const size_t HW = (size_t)Hd * Wd;
#pragma unroll
  for (int i = 0; i < 8; ++i) {
    const float* bc = pl + (size_t)(cgrp + i) * HW;
    float a = bc[(size_t)y0 * Wd + x0], b = bc[(size_t)y0 * Wd + x1];
    float c = bc[(size_t)y1 * Wd + x0], d = bc[(size_t)y1 * Wd + x1];
    o[i] = a * w00 + b * w01 + c * w10 + d * w11;
  }
}

template <int KSTEPS, int NCPW, bool RELU>
__device__ __forceinline__ void mfma_layer_fb(const unsigned short* inb, unsigned short* outb,
                                              const float* __restrict__ Wg,
                                              const float* __restrict__ bg, int N, int Kmax,
                                              int wid, int lane) {
  const int l15 = lane & 15;
  const int lhi = lane >> 4;
#pragma unroll
  for (int t = 0; t < NCPW; ++t) {
    const int nc = wid * NCPW + t;
    const int col = nc * 16 + l15;
    const float bias = bg[col];
    bf16x8 bfrag[KSTEPS];
#pragma unroll
    for (int ks = 0; ks < KSTEPS; ++ks) {
#pragma unroll
      for (int j = 0; j < 8; ++j) {
        const int k = ks * 32 + lhi * 8 + j;
        float wv = (k < Kmax) ? Wg[(size_t)k * N + col] : 0.0f;
        bfrag[ks][j] = (bf16_t)wv;
      }
    }
#pragma unroll
    for (int m = 0; m < 4; ++m) {
      f32x4 acc = {0.f, 0.f, 0.f, 0.f};
#pragma unroll
      for (int ks = 0; ks < KSTEPS; ++ks) {
        bf16x8 a = ld_frag(inb, m * 16 + l15, ks * 64 + lhi * 16);
        acc = __builtin_amdgcn_mfma_f32_16x16x32_bf16(a, bfrag[ks], acc, 0, 0, 0);
      }
      const int r0 = m * 16 + lhi * 4;
#pragma unroll
      for (int i = 0; i < 4; ++i) {
        float v = acc[i] + bias;
        if (RELU) v = fmaxf(v, 0.f);
        st_act(outb, r0 + i, col, v);
      }
    }
  }
}

__global__ __launch_bounds__(256) void KPlanes_fused_fb(
    const float* __restrict__ xyt, const float* __restrict__ yx, const float* __restrict__ xt,
    const float* __restrict__ yt, const float* __restrict__ fw1, const float* __restrict__ fb1,
    const float* __restrict__ fw2, const float* __restrict__ fb2, const float* __restrict__ w1,
    const float* __restrict__ b1, const float* __restrict__ w2, const float* __restrict__ b2,
    const float* __restrict__ w3, const float* __restrict__ b3, const float* __restrict__ w4,
    const float* __restrict__ b4, const int* __restrict__ fnum_p, float* __restrict__ out) {
  __shared__ unsigned short actA[64 * 256];
  __shared__ unsigned short actB[64 * 256];
  const int tid = threadIdx.x;
  const int lane = tid & 63;
  const int wid = tid >> 6;
  const float fnum = (float)(*fnum_p);
  {
    const int p = tid >> 2;
    const int cgrp = (tid & 3) * 8;
    const int pg = blockIdx.x * 64 + p;
    float x = xyt[pg * 3 + 0];
    float y = xyt[pg * 3 + 1];
    float t = xyt[pg * 3 + 2] / fnum;
    float syx[8], sxt[8], syt[8];
    sample8_f(yx, 540, 960, y, x, cgrp, syx);
    sample8_f(xt, 960, 300, x, t, cgrp, sxt);
    sample8_f(yt, 540, 300, y, t, cgrp, syt);
#pragma unroll
    for (int i = 0; i < 8; ++i) st_act(actA, p, cgrp + i, syx[i] * sxt[i] * syt[i]);
  }
  __syncthreads();
  mfma_layer_fb<1, 1, true>(actA, actB, fw1, fb1, 64, 32, wid, lane);
  __syncthreads();
  mfma_layer_fb<2, 1, true>(actB, actA, fw2, fb2, 64, 64, wid, lane);
  if (tid < 64) {
    const int pg = blockIdx.x * 64 + tid;
    float px = xyt[pg * 3 + 0];
    float py = xyt[pg * 3 + 1];
    float pt = xyt[pg * 3 + 2] / fnum;
    st_act(actA, tid, 64, py);
    st_act(actA, tid, 65, px);
    float sc = 1.f;
#pragma unroll
    for (int j = 0; j < 10; ++j) {
      st_act(actA, tid, 66 + j * 4 + 0, sinf(sc * py));
      st_act(actA, tid, 66 + j * 4 + 1, sinf(sc * px));
      st_act(actA, tid, 66 + j * 4 + 2, cosf(sc * py));
      st_act(actA, tid, 66 + j * 4 + 3, cosf(sc * px));
      sc *= 2.f;
    }
    st_act(actA, tid, 106, pt);
    sc = 1.f;
#pragma unroll
    for (int j = 0; j < 6; ++j) {
      st_act(actA, tid, 107 + j * 2, sinf(sc * pt));
      st_act(actA, tid, 108 + j * 2, cosf(sc * pt));
      sc *= 2.f;
    }
#pragma unroll
    for (int c = 119; c < 128; ++c) st_act(actA, tid, c, 0.f);
  }
  __syncthreads();
  mfma_layer_fb<4, 4, true>(actA, actB, w1, b1, 256, 119, wid, lane);
  __syncthreads();
  mfma_layer_fb<8, 4, true>(actB, actA, w2, b2, 256, 256, wid, lane);
  __syncthreads();
  mfma_layer_fb<8, 4, true>(actA, actB, w3, b3, 256, 256, wid, lane);
  __syncthreads();
  {
    const int p = tid >> 2, c = tid & 3;
    if (c < 3) {
      float acc = 0.f;
#pragma unroll
      for (int k0 = 0; k0 < 256; k0 += 8) {
        int b = swz(p, k0 * 2);
        uint4 u = *reinterpret_cast<const uint4*>(reinterpret_cast<const char*>(actB) + b);
        bf16x8 z = __builtin_bit_cast(bf16x8, u);
#pragma unroll
        for (int j = 0; j < 8; ++j) acc += (float)z[j] * w4[(k0 + j) * 3 + c];
      }
      acc += b4[c];
      out[(size_t)(blockIdx.x * 64 + p) * 3 + c] = 1.f / (1.f + expf(-acc));
    }
  }
}

extern "C" void kernel_launch(void* const* d_in, const int* in_sizes, int n_in, void* d_out,
                              int out_size, void* d_ws, size_t ws_size, hipStream_t stream) {
  const float* xyt = (const float*)d_in[0];
  const float* yx = (const float*)d_in[1];
  const float* xt = (const float*)d_in[2];
  const float* yt = (const float*)d_in[3];
  const float* fw1 = (const float*)d_in[4];
  const float* fb1 = (const float*)d_in[5];
  const float* fw2 = (const float*)d_in[6];
  const float* fb2 = (const float*)d_in[7];
  const float* w1 = (const float*)d_in[8];
  const float* b1 = (const float*)d_in[9];
  const float* w2 = (const float*)d_in[10];
  const float* b2 = (const float*)d_in[11];
  const float* w3 = (const float*)d_in[12];
  const float* b3 = (const float*)d_in[13];
  const float* w4 = (const float*)d_in[14];
  const float* b4 = (const float*)d_in[15];
  const int* fnum = (const int*)d_in[16];
  float* out = (float*)d_out;

  const int hw_yx = 540 * 960, hw_xt = 960 * 300, hw_yt = 540 * 300;
  const size_t plane_bytes = ((size_t)hw_yx + hw_xt + hw_yt) * 64;  // fp16, 64B/site
  const size_t wfrag_bytes = (size_t)340 * 64 * sizeof(uint4);
  const size_t need = plane_bytes + wfrag_bytes;

  char* ws = (char*)d_ws;
  uint2* yx_h = (uint2*)ws;
  uint2* xt_h = (uint2*)(ws + (size_t)hw_yx * 64);
  uint2* yt_h = (uint2*)(ws + (size_t)(hw_yx + hw_xt) * 64);
  uint4* wbase = (uint4*)(ws + plane_bytes);
  uint4* wf1 = wbase + 0 * 64;
  uint4* wf2 = wbase + 4 * 64;
  uint4* wf3 = wbase + 12 * 64;
  uint4* wf4 = wbase + 76 * 64;
  uint4* wf5 = wbase + 204 * 64;
  uint4* wf6 = wbase + 332 * 64;

  if (ws_size >= need) {
    const int nb_tr = 2025 + 1125 + 633;
    KPlanes_tr3<<<nb_tr, 256, 0, stream>>>(yx, xt, yt, (uint4*)yx_h, (uint4*)xt_h, (uint4*)yt_h);
    KPlanes_packall<<<85, 256, 0, stream>>>(fw1, fw2, w1, w2, w3, w4, wbase);
    KPlanes_fused5<<<NBLK, NTHR, 0, stream>>>(xyt, yx_h, xt_h, yt_h, wf1, fb1, wf2, fb2, wf3, b1,
                                              wf4, b2, wf5, b3, wf6, b4, fnum, out);
  } else {
    KPlanes_fused_fb<<<1048576 / 64, 256, 0, stream>>>(xyt, yx, xt, yt, fw1, fb1, fw2, fb2, w1,
                                                       b1, w2, b2, w3, b3, w4, b4, fnum, out);
  }
}

// Round 6
// 476.945 us; speedup vs baseline: 2.4925x; 2.0062x over previous
//
#include <hip/hip_runtime.h>

typedef __bf16 bf16_t;
typedef __bf16 bf16x8 __attribute__((ext_vector_type(8)));
typedef _Float16 f16x4 __attribute__((ext_vector_type(4)));
typedef unsigned short u16x8 __attribute__((ext_vector_type(8)));
typedef unsigned short u16x4 __attribute__((ext_vector_type(4)));
typedef float f32x4 __attribute__((ext_vector_type(4)));

#define MT 64
#define NTHR 512
#define NBLK (1048576 / MT)

// LDS row stride = 256 cols * 2B = 512B. XOR-swizzle 16B slots by row.
__device__ __forceinline__ int swz(int row, int colbyte) {
  return row * 512 + (colbyte ^ ((row & 31) << 4));
}
__device__ __forceinline__ void st_act(unsigned short* buf, int row, int col, float v) {
  buf[swz(row, col * 2) >> 1] = __builtin_bit_cast(unsigned short, (bf16_t)v);
}
// store 4 consecutive cols (col multiple of 4) as one 8B write inside a 16B slot
__device__ __forceinline__ void st_act4(unsigned short* buf, int row, int col, float v0, float v1,
                                        float v2, float v3) {
  u16x4 pk;
  pk[0] = __builtin_bit_cast(unsigned short, (bf16_t)v0);
  pk[1] = __builtin_bit_cast(unsigned short, (bf16_t)v1);
  pk[2] = __builtin_bit_cast(unsigned short, (bf16_t)v2);
  pk[3] = __builtin_bit_cast(unsigned short, (bf16_t)v3);
  *reinterpret_cast<uint2*>(reinterpret_cast<char*>(buf) + swz(row, col * 2)) =
      __builtin_bit_cast(uint2, pk);
}
__device__ __forceinline__ bf16x8 ld_frag(const unsigned short* buf, int row, int kbyte) {
  const uint4 u =
      *reinterpret_cast<const uint4*>(reinterpret_cast<const char*>(buf) + swz(row, kbyte));
  return __builtin_bit_cast(bf16x8, u);
}

// ---------- prologue 1: transpose all 3 planes (32,H,W) fp32 -> (H*W,32) fp16 --
__global__ void KPlanes_tr3(const float* __restrict__ yx, const float* __restrict__ xt,
                            const float* __restrict__ yt, uint4* __restrict__ d0,
                            uint4* __restrict__ d1, uint4* __restrict__ d2) {
  const int HW0 = 518400, HW1 = 288000, HW2 = 162000;
  const int NB0 = 2025, NB1 = 1125;
  const int b = blockIdx.x;
  const float* src;
  uint4* dst;
  int HW, s;
  if (b < NB0) {
    src = yx; dst = d0; HW = HW0; s = b * 256 + threadIdx.x;
  } else if (b < NB0 + NB1) {
    src = xt; dst = d1; HW = HW1; s = (b - NB0) * 256 + threadIdx.x;
  } else {
    src = yt; dst = d2; HW = HW2; s = (b - NB0 - NB1) * 256 + threadIdx.x;
  }
  if (s >= HW) return;
#pragma unroll
  for (int g = 0; g < 4; ++g) {
    u16x8 v;
#pragma unroll
    for (int j = 0; j < 8; ++j) {
      const float w = src[(size_t)(g * 8 + j) * HW + s];
      v[j] = __builtin_bit_cast(unsigned short, (_Float16)w);
    }
    dst[(size_t)s * 4 + g] = __builtin_bit_cast(uint4, v);
  }
}

// ---------- prologue 2: pack ALL fp32 weights into bf16 MFMA fragments --------
// lane holds col(neuron)=g*16+(lane&15), k=ks*32+(lane>>4)*8+j  (A- or B-usable)
__global__ void KPlanes_packall(const float* __restrict__ fw1, const float* __restrict__ fw2,
                                const float* __restrict__ w1, const float* __restrict__ w2,
                                const float* __restrict__ w3, const float* __restrict__ w4,
                                uint4* __restrict__ dst) {
  const int F = blockIdx.x * 4 + (threadIdx.x >> 6);
  const int lane = threadIdx.x & 63;
  if (F >= 340) return;
  const float* W;
  int N, K, KS, fbase;
  if (F < 4)        { W = fw1; N = 64;  K = 32;  KS = 1; fbase = 0; }
  else if (F < 12)  { W = fw2; N = 64;  K = 64;  KS = 2; fbase = 4; }
  else if (F < 76)  { W = w1;  N = 256; K = 119; KS = 4; fbase = 12; }
  else if (F < 204) { W = w2;  N = 256; K = 256; KS = 8; fbase = 76; }
  else if (F < 332) { W = w3;  N = 256; K = 256; KS = 8; fbase = 204; }
  else              { W = w4;  N = 3;   K = 256; KS = 8; fbase = 332; }
  const int f = F - fbase;
  const int g = f / KS, ks = f - g * KS;
  const int col = g * 16 + (lane & 15);
  u16x8 v;
#pragma unroll
  for (int j = 0; j < 8; ++j) {
    const int k = ks * 32 + (lane >> 4) * 8 + j;
    const float w = (k < K && col < N) ? W[(size_t)k * N + col] : 0.0f;
    v[j] = __builtin_bit_cast(unsigned short, (bf16_t)w);
  }
  dst[(size_t)F * 64 + lane] = __builtin_bit_cast(uint4, v);
}

// ---------- fp16 bilinear sample, 4 channels per thread -----------------------
struct Smp4 {
  uint2 c00, c01, c10, c11;
  float w00, w01, w10, w11;
};
__device__ __forceinline__ Smp4 sample_ld4(const uint2* __restrict__ plt, int Hd, int Wd, float u,
                                           float v, int q) {
  Smp4 s;
  float ix = fminf(fmaxf(u * (float)Wd - 0.5f, 0.f), (float)Wd - 1.f);
  float iy = fminf(fmaxf(v * (float)Hd - 0.5f, 0.f), (float)Hd - 1.f);
  float x0f = floorf(ix), y0f = floorf(iy);
  float wx = ix - x0f, wy = iy - y0f;
  int x0 = (int)x0f, y0 = (int)y0f;
  int x1 = min(x0 + 1, Wd - 1), y1 = min(y0 + 1, Hd - 1);
  s.w00 = (1.f - wx) * (1.f - wy);
  s.w01 = wx * (1.f - wy);
  s.w10 = (1.f - wx) * wy;
  s.w11 = wx * wy;
  const size_t r0 = (size_t)y0 * Wd, r1 = (size_t)y1 * Wd;
  s.c00 = plt[(r0 + x0) * 8 + q];
  s.c01 = plt[(r0 + x1) * 8 + q];
  s.c10 = plt[(r1 + x0) * 8 + q];
  s.c11 = plt[(r1 + x1) * 8 + q];
  return s;
}
__device__ __forceinline__ void smp_combine4(const Smp4& s, float* o) {
  const f16x4 a = __builtin_bit_cast(f16x4, s.c00);
  const f16x4 b = __builtin_bit_cast(f16x4, s.c01);
  const f16x4 c = __builtin_bit_cast(f16x4, s.c10);
  const f16x4 d = __builtin_bit_cast(f16x4, s.c11);
#pragma unroll
  for (int i = 0; i < 4; ++i)
    o[i] = (float)a[i] * s.w00 + (float)b[i] * s.w01 + (float)c[i] * s.w10 + (float)d[i] * s.w11;
}

// ---------- ping-pong MFMA layer, swapped operands (D = W x act) --------------
// D: lane = point col, rows = 4 consecutive neurons -> b64 stores + float4 bias.
// ks-outer loop: weight frags transient, acc[MTPW][NT] = 4*MTPW*NT regs.
template <int KS, int NT, int MTPW, bool RELU>
__device__ __forceinline__ void layer_pp(const unsigned short* in, unsigned short* outb,
                                         const uint4* __restrict__ Wf,
                                         const float* __restrict__ bg, int gbase, int moff,
                                         int lane) {
  const int l15 = lane & 15, lhi = lane >> 4;
  f32x4 acc[MTPW][NT];
#pragma unroll
  for (int m = 0; m < MTPW; ++m)
#pragma unroll
    for (int t = 0; t < NT; ++t) acc[m][t] = f32x4{0.f, 0.f, 0.f, 0.f};
#pragma unroll
  for (int ks = 0; ks < KS; ++ks) {
    bf16x8 wa[NT];
#pragma unroll
    for (int t = 0; t < NT; ++t)
      wa[t] = __builtin_bit_cast(bf16x8, Wf[(size_t)((gbase + t) * KS + ks) * 64 + lane]);
#pragma unroll
    for (int m = 0; m < MTPW; ++m) {
      const bf16x8 b = ld_frag(in, (moff + m) * 16 + l15, ks * 64 + lhi * 16);
#pragma unroll
      for (int t = 0; t < NT; ++t)
        acc[m][t] = __builtin_amdgcn_mfma_f32_16x16x32_bf16(wa[t], b, acc[m][t], 0, 0, 0);
    }
  }
#pragma unroll
  for (int t = 0; t < NT; ++t) {
    const int ncol = (gbase + t) * 16 + lhi * 4;
    const float4 b4 = *reinterpret_cast<const float4*>(&bg[ncol]);
#pragma unroll
    for (int m = 0; m < MTPW; ++m) {
      const int row = (moff + m) * 16 + l15;
      float v0 = acc[m][t][0] + b4.x, v1 = acc[m][t][1] + b4.y;
      float v2 = acc[m][t][2] + b4.z, v3 = acc[m][t][3] + b4.w;
      if (RELU) {
        v0 = fmaxf(v0, 0.f); v1 = fmaxf(v1, 0.f);
        v2 = fmaxf(v2, 0.f); v3 = fmaxf(v3, 0.f);
      }
      st_act4(outb, row, ncol, v0, v1, v2, v3);
    }
  }
}

// ---------- main fused kernel: 64 pts/block, 8 waves, 64 KB LDS, 2 blk/CU -----
__global__ __launch_bounds__(NTHR, 4) void KPlanes_fused6(
    const float* __restrict__ xyt, const uint2* __restrict__ yx_h, const uint2* __restrict__ xt_h,
    const uint2* __restrict__ yt_h, const uint4* __restrict__ wf1, const float* __restrict__ fb1,
    const uint4* __restrict__ wf2, const float* __restrict__ fb2, const uint4* __restrict__ wf3,
    const float* __restrict__ b1, const uint4* __restrict__ wf4, const float* __restrict__ b2,
    const uint4* __restrict__ wf5, const float* __restrict__ b3, const uint4* __restrict__ wf6,
    const float* __restrict__ b4, const int* __restrict__ fnum_p, float* __restrict__ out) {
  __shared__ unsigned short actA[MT * 256];  // 32 KB
  __shared__ unsigned short actB[MT * 256];  // 32 KB
  const int tid = threadIdx.x;
  const int lane = tid & 63;
  const int wid = tid >> 6;
  const float rfn = 1.0f / (float)(*fnum_p);

  // ---- phase 0: gather (8 thr/point, 4 ch each) + pos-enc, into actA
  {
    const int p = tid >> 3;
    const int q = tid & 7;
    const int pg = blockIdx.x * MT + p;
    const float x = xyt[pg * 3 + 0];
    const float y = xyt[pg * 3 + 1];
    const float t = xyt[pg * 3 + 2] * rfn;
    Smp4 sYX = sample_ld4(yx_h, 540, 960, y, x, q);
    Smp4 sXT = sample_ld4(xt_h, 960, 300, x, t, q);
    Smp4 sYT = sample_ld4(yt_h, 540, 300, y, t, q);
    // pos-enc on q=4..7 (overlaps gather latency); one sincosf + double-angle
    if (q == 4) {
      st_act(actA, p, 64, y);
      float sj, cj;
      sincosf(y, &sj, &cj);
#pragma unroll
      for (int j = 0; j < 10; ++j) {
        st_act(actA, p, 66 + j * 4, sj);
        st_act(actA, p, 68 + j * 4, cj);
        const float ns = 2.f * sj * cj;
        cj = fmaf(-2.f * sj, sj, 1.f);
        sj = ns;
      }
    } else if (q == 5) {
      st_act(actA, p, 65, x);
      float sj, cj;
      sincosf(x, &sj, &cj);
#pragma unroll
      for (int j = 0; j < 10; ++j) {
        st_act(actA, p, 67 + j * 4, sj);
        st_act(actA, p, 69 + j * 4, cj);
        const float ns = 2.f * sj * cj;
        cj = fmaf(-2.f * sj, sj, 1.f);
        sj = ns;
      }
    } else if (q == 6) {
      st_act(actA, p, 106, t);
      float sj, cj;
      sincosf(t, &sj, &cj);
#pragma unroll
      for (int j = 0; j < 6; ++j) {
        st_act(actA, p, 107 + 2 * j, sj);
        st_act(actA, p, 108 + 2 * j, cj);
        const float ns = 2.f * sj * cj;
        cj = fmaf(-2.f * sj, sj, 1.f);
        sj = ns;
      }
    } else if (q == 7) {
      st_act(actA, p, 119, 0.f);
      st_act4(actA, p, 120, 0.f, 0.f, 0.f, 0.f);
      st_act4(actA, p, 124, 0.f, 0.f, 0.f, 0.f);
    }
    float a4[4], b4_[4], c4[4];
    smp_combine4(sYX, a4);
    smp_combine4(sXT, b4_);
    smp_combine4(sYT, c4);
    st_act4(actA, p, q * 4, a4[0] * b4_[0] * c4[0], a4[1] * b4_[1] * c4[1],
            a4[2] * b4_[2] * c4[2], a4[3] * b4_[3] * c4[3]);
  }
  __syncthreads();
  // L1: feat(32)->h1(64), A->B. 4 n-groups x 2 m-pairs over 8 waves.
  layer_pp<1, 1, 2, true>(actA, actB, wf1, fb1, wid & 3, (wid >> 2) * 2, lane);
  __syncthreads();
  // L2: h1(64)->h2(64), B->A cols 0..63 (pe cols 64..127 in A preserved)
  layer_pp<2, 1, 2, true>(actB, actA, wf2, fb2, wid & 3, (wid >> 2) * 2, lane);
  __syncthreads();
  // L3: [h2|pe](119 pad 128)->z1(256), A->B. wave: 2 n-groups, all 4 m-groups.
  layer_pp<4, 2, 4, true>(actA, actB, wf3, b1, wid * 2, 0, lane);
  __syncthreads();
  // L4: z1->z2(256), B->A
  layer_pp<8, 2, 4, true>(actB, actA, wf4, b2, wid * 2, 0, lane);
  __syncthreads();
  // L5: z2->z3(256), A->B
  layer_pp<8, 2, 4, true>(actA, actB, wf5, b3, wid * 2, 0, lane);
  __syncthreads();
  // L6: z3(256)->3 (pad 16), B->global. Waves 0..3 own the 4 point-groups.
  if (wid < 4) {
    const int l15 = lane & 15, lhi = lane >> 4;
    f32x4 acc = {0.f, 0.f, 0.f, 0.f};
#pragma unroll
    for (int ks = 0; ks < 8; ++ks) {
      const bf16x8 wa = __builtin_bit_cast(bf16x8, wf6[ks * 64 + lane]);
      acc = __builtin_amdgcn_mfma_f32_16x16x32_bf16(
          wa, ld_frag(actB, wid * 16 + l15, ks * 64 + lhi * 16), acc, 0, 0, 0);
    }
    if (lhi == 0) {
      const size_t pg = (size_t)blockIdx.x * MT + wid * 16 + l15;
#pragma unroll
      for (int i = 0; i < 3; ++i) {
        const float v = acc[i] + b4[i];
        out[pg * 3 + i] = 1.f / (1.f + expf(-v));
      }
    }
  }
}

// ================= fallback (fp32 weights, direct plane sampling) =============
__device__ __forceinline__ void sample8_f(const float* __restrict__ pl, int Hd, int Wd, float u,
                                          float v, int cgrp, float* o) {
  float ix = fminf(fmaxf(u * (float)Wd - 0.5f, 0.f), (float)Wd - 1.f);
  float iy = fminf(fmaxf(v * (float)Hd - 0.5f, 0.f), (float)Hd - 1.f);
  float x0f = floorf(ix), y0f = floorf(iy);
  float wx = ix - x0f, wy = iy - y0f;
  int x0 = (int)x0f, y0 = (int)y0f;
  int x1 = min(x0 + 1, Wd - 1), y1 = min(y0 + 1, Hd - 1);
  float w00 = (1.f - wx) * (1.f - wy), w01 = wx * (1.f - wy);
  float w10 = (1.f - wx) * wy, w11 = wx * wy;
  const size_t HW = (size_t)Hd * Wd;
#pragma unroll
  for (int i = 0; i < 8; ++i) {
    const float* bc = pl + (size_t)(cgrp + i) * HW;
    float a = bc[(size_t)y0 * Wd + x0], b = bc[(size_t)y0 * Wd + x1];
    float c = bc[(size_t)y1 * Wd + x0], d = bc[(size_t)y1 * Wd + x1];
    o[i] = a * w00 + b * w01 + c * w10 + d * w11;
  }
}

template <int KSTEPS, int NCPW, bool RELU>
__device__ __forceinline__ void mfma_layer_fb(const unsigned short* inb, unsigned short* outb,
                                              const float* __restrict__ Wg,
                                              const float* __restrict__ bg, int N, int Kmax,
                                              int wid, int lane) {
  const int l15 = lane & 15;
  const int lhi = lane >> 4;
#pragma unroll
  for (int t = 0; t < NCPW; ++t) {
    const int nc = wid * NCPW + t;
    const int col = nc * 16 + l15;
    const float bias = bg[col];
    bf16x8 bfrag[KSTEPS];
#pragma unroll
    for (int ks = 0; ks < KSTEPS; ++ks) {
#pragma unroll
      for (int j = 0; j < 8; ++j) {
        const int k = ks * 32 + lhi * 8 + j;
        float wv = (k < Kmax) ? Wg[(size_t)k * N + col] : 0.0f;
        bfrag[ks][j] = (bf16_t)wv;
      }
    }
#pragma unroll
    for (int m = 0; m < 4; ++m) {
      f32x4 acc = {0.f, 0.f, 0.f, 0.f};
#pragma unroll
      for (int ks = 0; ks < KSTEPS; ++ks) {
        bf16x8 a = ld_frag(inb, m * 16 + l15, ks * 64 + lhi * 16);
        acc = __builtin_amdgcn_mfma_f32_16x16x32_bf16(a, bfrag[ks], acc, 0, 0, 0);
      }
      const int r0 = m * 16 + lhi * 4;
#pragma unroll
      for (int i = 0; i < 4; ++i) {
        float v = acc[i] + bias;
        if (RELU) v = fmaxf(v, 0.f);
        st_act(outb, r0 + i, col, v);
      }
    }
  }
}

__global__ __launch_bounds__(256) void KPlanes_fused_fb(
    const float* __restrict__ xyt, const float* __restrict__ yx, const float* __restrict__ xt,
    const float* __restrict__ yt, const float* __restrict__ fw1, const float* __restrict__ fb1,
    const float* __restrict__ fw2, const float* __restrict__ fb2, const float* __restrict__ w1,
    const float* __restrict__ b1, const float* __restrict__ w2, const float* __restrict__ b2,
    const float* __restrict__ w3, const float* __restrict__ b3, const float* __restrict__ w4,
    const float* __restrict__ b4, const int* __restrict__ fnum_p, float* __restrict__ out) {
  __shared__ unsigned short actA[64 * 256];
  __shared__ unsigned short actB[64 * 256];
  const int tid = threadIdx.x;
  const int lane = tid & 63;
  const int wid = tid >> 6;
  const float fnum = (float)(*fnum_p);
  {
    const int p = tid >> 2;
    const int cgrp = (tid & 3) * 8;
    const int pg = blockIdx.x * 64 + p;
    float x = xyt[pg * 3 + 0];
    float y = xyt[pg * 3 + 1];
    float t = xyt[pg * 3 + 2] / fnum;
    float syx[8], sxt[8], syt[8];
    sample8_f(yx, 540, 960, y, x, cgrp, syx);
    sample8_f(xt, 960, 300, x, t, cgrp, sxt);
    sample8_f(yt, 540, 300, y, t, cgrp, syt);
#pragma unroll
    for (int i = 0; i < 8; ++i) st_act(actA, p, cgrp + i, syx[i] * sxt[i] * syt[i]);
  }
  __syncthreads();
  mfma_layer_fb<1, 1, true>(actA, actB, fw1, fb1, 64, 32, wid, lane);
  __syncthreads();
  mfma_layer_fb<2, 1, true>(actB, actA, fw2, fb2, 64, 64, wid, lane);
  if (tid < 64) {
    const int pg = blockIdx.x * 64 + tid;
    float px = xyt[pg * 3 + 0];
    float py = xyt[pg * 3 + 1];
    float pt = xyt[pg * 3 + 2] / fnum;
    st_act(actA, tid, 64, py);
    st_act(actA, tid, 65, px);
    float sc = 1.f;
#pragma unroll
    for (int j = 0; j < 10; ++j) {
      st_act(actA, tid, 66 + j * 4 + 0, sinf(sc * py));
      st_act(actA, tid, 66 + j * 4 + 1, sinf(sc * px));
      st_act(actA, tid, 66 + j * 4 + 2, cosf(sc * py));
      st_act(actA, tid, 66 + j * 4 + 3, cosf(sc * px));
      sc *= 2.f;
    }
    st_act(actA, tid, 106, pt);
    sc = 1.f;
#pragma unroll
    for (int j = 0; j < 6; ++j) {
      st_act(actA, tid, 107 + j * 2, sinf(sc * pt));
      st_act(actA, tid, 108 + j * 2, cosf(sc * pt));
      sc *= 2.f;
    }
#pragma unroll
    for (int c = 119; c < 128; ++c) st_act(actA, tid, c, 0.f);
  }
  __syncthreads();
  mfma_layer_fb<4, 4, true>(actA, actB, w1, b1, 256, 119, wid, lane);
  __syncthreads();
  mfma_layer_fb<8, 4, true>(actB, actA, w2, b2, 256, 256, wid, lane);
  __syncthreads();
  mfma_layer_fb<8, 4, true>(actA, actB, w3, b3, 256, 256, wid, lane);
  __syncthreads();
  {
    const int p = tid >> 2, c = tid & 3;
    if (c < 3) {
      float acc = 0.f;
#pragma unroll
      for (int k0 = 0; k0 < 256; k0 += 8) {
        int b = swz(p, k0 * 2);
        uint4 u = *reinterpret_cast<const uint4*>(reinterpret_cast<const char*>(actB) + b);
        bf16x8 z = __builtin_bit_cast(bf16x8, u);
#pragma unroll
        for (int j = 0; j < 8; ++j) acc += (float)z[j] * w4[(k0 + j) * 3 + c];
      }
      acc += b4[c];
      out[(size_t)(blockIdx.x * 64 + p) * 3 + c] = 1.f / (1.f + expf(-acc));
    }
  }
}

extern "C" void kernel_launch(void* const* d_in, const int* in_sizes, int n_in, void* d_out,
                              int out_size, void* d_ws, size_t ws_size, hipStream_t stream) {
  const float* xyt = (const float*)d_in[0];
  const float* yx = (const float*)d_in[1];
  const float* xt = (const float*)d_in[2];
  const float* yt = (const float*)d_in[3];
  const float* fw1 = (const float*)d_in[4];
  const float* fb1 = (const float*)d_in[5];
  const float* fw2 = (const float*)d_in[6];
  const float* fb2 = (const float*)d_in[7];
  const float* w1 = (const float*)d_in[8];
  const float* b1 = (const float*)d_in[9];
  const float* w2 = (const float*)d_in[10];
  const float* b2 = (const float*)d_in[11];
  const float* w3 = (const float*)d_in[12];
  const float* b3 = (const float*)d_in[13];
  const float* w4 = (const float*)d_in[14];
  const float* b4 = (const float*)d_in[15];
  const int* fnum = (const int*)d_in[16];
  float* out = (float*)d_out;

  const int hw_yx = 540 * 960, hw_xt = 960 * 300, hw_yt = 540 * 300;
  const size_t plane_bytes = ((size_t)hw_yx + hw_xt + hw_yt) * 64;  // fp16, 64B/site
  const size_t wfrag_bytes = (size_t)340 * 64 * sizeof(uint4);
  const size_t need = plane_bytes + wfrag_bytes;

  char* ws = (char*)d_ws;
  uint2* yx_h = (uint2*)ws;
  uint2* xt_h = (uint2*)(ws + (size_t)hw_yx * 64);
  uint2* yt_h = (uint2*)(ws + (size_t)(hw_yx + hw_xt) * 64);
  uint4* wbase = (uint4*)(ws + plane_bytes);
  uint4* wf1 = wbase + 0 * 64;
  uint4* wf2 = wbase + 4 * 64;
  uint4* wf3 = wbase + 12 * 64;
  uint4* wf4 = wbase + 76 * 64;
  uint4* wf5 = wbase + 204 * 64;
  uint4* wf6 = wbase + 332 * 64;

  if (ws_size >= need) {
    const int nb_tr = 2025 + 1125 + 633;
    KPlanes_tr3<<<nb_tr, 256, 0, stream>>>(yx, xt, yt, (uint4*)yx_h, (uint4*)xt_h, (uint4*)yt_h);
    KPlanes_packall<<<85, 256, 0, stream>>>(fw1, fw2, w1, w2, w3, w4, wbase);
    KPlanes_fused6<<<NBLK, NTHR, 0, stream>>>(xyt, yx_h, xt_h, yt_h, wf1, fb1, wf2, fb2, wf3, b1,
                                              wf4, b2, wf5, b3, wf6, b4, fnum, out);
  } else {
    KPlanes_fused_fb<<<1048576 / 64, 256, 0, stream>>>(xyt, yx, xt, yt, fw1, fb1, fw2, fb2, w1,
                                                       b1, w2, b2, w3, b3, w4, b4, fnum, out);
  }
}